// Round 5
// 136.559 us; speedup vs baseline: 1.3015x; 1.3015x over previous
//
#include <hip/hip_runtime.h>

// x: [B=64, C=2048, J=8] fp32 ; W: [K=32, C=2048, I=16, J=8] fp32
// out v: [B=64, K=32, I=16] fp32
#define Bn 64
#define Cn 2048
#define Kn 32
#define In 16
#define EPSf 1e-7f

#define NOUT (Bn * Kn * In)   // 32768
#define KJ   (Cn * 8)         // 16384 = (c,j) contraction length
#define KS1  64               // kGemm1 k-splits (8 ksteps of 32 each)
#define KS2  32               // kGemm2 k-splits (16 ksteps of 32 each)

typedef short bf8v __attribute__((ext_vector_type(8)));   // 8 bf16 in 4 VGPRs
typedef float f4v  __attribute__((ext_vector_type(4)));

union U16B { uint4 u; bf8v v; unsigned short h[8]; };

__device__ __forceinline__ unsigned short f2bf(float f) {
    unsigned u = __float_as_uint(f);
    u += 0x7FFF + ((u >> 16) & 1);          // round-to-nearest-even
    return (unsigned short)(u >> 16);
}
// 2 f32 -> packed bf16x2 (RNE). No builtin on gfx950; single VOP3 instr.
__device__ __forceinline__ unsigned cvtpk(float lo, float hi) {
    unsigned r;
    asm("v_cvt_pk_bf16_f32 %0, %1, %2" : "=v"(r) : "v"(lo), "v"(hi));
    return r;
}
__device__ __forceinline__ float bflo(unsigned u) { return __uint_as_float(u << 16); }
__device__ __forceinline__ float bfhi(unsigned u) { return __uint_as_float(u & 0xffff0000u); }

// ---------------------------------------------------------------------------
// kPrepX: x fp32 -> xb bf16 [b][cj] (A-frag natural order) AND
//         xT2 bf16 [cj/4][b][4] (transposed-packed, for kAgr's epilogue:
//         lane reads its 4 consecutive cj rows for one b as a single 8B load).
// ---------------------------------------------------------------------------
__global__ __launch_bounds__(256) void kPrepX(const float* __restrict__ x,
                                              unsigned short* __restrict__ xb,
                                              unsigned short* __restrict__ xT2)
{
    const int g = blockIdx.x * 256 + threadIdx.x;        // 0..131071 = b*2048+c
    const float4* s = (const float4*)(x + (size_t)g * 8);
    float4 a = s[0], b4 = s[1];
    U16B o;
    o.h[0] = f2bf(a.x);  o.h[1] = f2bf(a.y);  o.h[2] = f2bf(a.z);  o.h[3] = f2bf(a.w);
    o.h[4] = f2bf(b4.x); o.h[5] = f2bf(b4.y); o.h[6] = f2bf(b4.z); o.h[7] = f2bf(b4.w);
    ((uint4*)xb)[g] = o.u;
    const int b = g >> 11, c = g & 2047;
    *(uint2*)(xT2 + ((size_t)(c * 2 + 0) * 64 + b) * 4) = make_uint2(o.u.x, o.u.y);
    *(uint2*)(xT2 + ((size_t)(c * 2 + 1) * 64 + b) * 4) = make_uint2(o.u.z, o.u.w);
}

// ---------------------------------------------------------------------------
// kGemm1: S1 partials via MFMA.  D[b, n=(k,i)] = sum_cj x[b,cj] * W[cj,n].
// B-fragments assembled on the fly from fp32 W via v_cvt_pk_bf16_f32 — this
// removes kPrepW entirely (old: 32r+16w prep + 16r read; new: 32r once).
// Grid 512 = 8 nstrips x 64 ksplits; 4 waves = 4 m-tiles (all of B).
// ---------------------------------------------------------------------------
__global__ __launch_bounds__(256) void kGemm1(const unsigned short* __restrict__ xb,
                                              const float* __restrict__ W,
                                              float* __restrict__ part1)
{
    const int nstrip = blockIdx.x & 7;
    const int ksplit = blockIdx.x >> 3;       // 0..63
    const int ks0    = ksplit * 8;
    const int lane   = threadIdx.x & 63;
    const int m0     = (threadIdx.x >> 6) * 16;
    const int i      = lane & 15;             // B col within k-tile
    const int cq     = lane >> 4;             // c-quad within kstep

    f4v acc[4] = {};
    const unsigned short* arow = xb + (size_t)(m0 + (lane & 15)) * KJ + cq * 8;

    for (int s = 0; s < 8; ++s) {
        const int ks = ks0 + s;
        U16B af;
        af.u = *(const uint4*)(arow + (size_t)ks * 32);
        const int c = ks * 4 + cq;
        #pragma unroll
        for (int t = 0; t < 4; ++t) {
            const int ko = nstrip * 4 + t;    // n-tile == output capsule k
            const float* wp = W + (((size_t)ko * Cn + c) * 16 + i) * 8;
            const float4 w0 = *(const float4*)wp;
            const float4 w1 = *(const float4*)(wp + 4);
            U16B bf;
            bf.u.x = cvtpk(w0.x, w0.y); bf.u.y = cvtpk(w0.z, w0.w);
            bf.u.z = cvtpk(w1.x, w1.y); bf.u.w = cvtpk(w1.z, w1.w);
            acc[t] = __builtin_amdgcn_mfma_f32_16x16x32_bf16(af.v, bf.v, acc[t], 0, 0, 0);
        }
    }

    // C/D layout: col = lane&15, row = (lane>>4)*4 + reg (verified m89/m91)
    float* pb = part1 + (size_t)ksplit * NOUT;
    const int col = lane & 15, rbase = (lane >> 4) * 4;
    #pragma unroll
    for (int t = 0; t < 4; ++t) {
        const int n = (nstrip * 4 + t) * 16 + col;
        #pragma unroll
        for (int r = 0; r < 4; ++r)
            pb[(size_t)(m0 + rbase + r) * 512 + n] = acc[t][r];
    }
}

// ---------------------------------------------------------------------------
// kSq1: v1 = squash((1/32) * sum_splits part1); emit v1 ONLY as bf16
// B-fragments v1f[k][ntile][lane<32][8] for kAgr (i>=16 lanes are padding).
// 32768 threads (one per (b,k,i)), coalesced scalar stream.
// ---------------------------------------------------------------------------
__global__ __launch_bounds__(256) void kSq1(const float* __restrict__ part1,
                                            unsigned short* __restrict__ v1f)
{
    const int t = blockIdx.x * 256 + threadIdx.x;   // 0..32767 = ((b*32)+k)*16+i
    float s = 0.f;
    #pragma unroll 8
    for (int g = 0; g < KS1; ++g) s += part1[(size_t)g * NOUT + t];
    s *= (1.0f / 32.0f);                            // softmax(0) over k = 1/32
    float sq = s * s;                               // reduce over the 16 i's
    sq += __shfl_xor(sq, 1);
    sq += __shfl_xor(sq, 2);
    sq += __shfl_xor(sq, 4);
    sq += __shfl_xor(sq, 8);
    const float f = (sq / (1.0f + sq)) * rsqrtf(sq + EPSf);
    const float v = s * f;
    const int b = t >> 9, k = (t >> 4) & 31, i = t & 15;
    // B-frag slot: n=lane&15=b&15, kdim=(lane>>4)*8+t  ->  lane=(i>>3)*16+(b&15)
    const int pos = ((k * 4 + (b >> 4)) * 32 + (i >> 3) * 16 + (b & 15)) * 8 + (i & 7);
    v1f[pos] = f2bf(v);
}

// ---------------------------------------------------------------------------
// kAgr: agreement via MFMA without materializing u or wv.
// Per k: D[m=(c,j), n=b] = sum_i W[k,c,i,j]*v1[b,k,i]  (i padded 16->32 with
// zero lanes), then epilogue A[b,k,c] = sum_j x[b,c,j]*D[(c,j),b] via 4 FMA
// + shfl_xor(16).  Output agr[k][c][b] fp32 (softmaxed in place by kSmax).
// Grid 1024 = 32 k x 32 c-groups (64 c each).
// ---------------------------------------------------------------------------
__global__ __launch_bounds__(256) void kAgr(const float* __restrict__ W,
                                            const unsigned short* __restrict__ v1f,
                                            const unsigned short* __restrict__ xT2,
                                            float* __restrict__ agr)
{
    const int ko   = blockIdx.x & 31;
    const int cg   = blockIdx.x >> 5;          // 0..31
    const int lane = threadIdx.x & 63;
    const int w    = threadIdx.x >> 6;

    // v1 B-frags for the 4 b-tiles; lanes>=32 are the i>=16 zero padding.
    U16B bfr[4];
    #pragma unroll
    for (int nt = 0; nt < 4; ++nt) {
        if (lane < 32)
            bfr[nt].u = *(const uint4*)(v1f + ((size_t)(ko * 4 + nt) * 32 + lane) * 8);
        else
            bfr[nt].u = make_uint4(0, 0, 0, 0);
    }

    for (int mt = w; mt < 32; mt += 4) {       // 8 m-tiles per wave
        const int cjb = cg * 512 + mt * 16;
        U16B afr;                               // A-frag: m=cj, kdim=i (pad>=16)
        if (lane < 32) {
            const int cj = cjb + (lane & 15);
            const int c = cj >> 3, j = cj & 7;
            const int ib = (lane >> 4) * 8;
            const float* wp = W + (((size_t)ko * Cn + c) * 16 + ib) * 8 + j;
            afr.u.x = cvtpk(wp[0],  wp[8]);
            afr.u.y = cvtpk(wp[16], wp[24]);
            afr.u.z = cvtpk(wp[32], wp[40]);
            afr.u.w = cvtpk(wp[48], wp[56]);
        } else afr.u = make_uint4(0, 0, 0, 0);

        const int xrow = (cjb >> 2) + (lane >> 4);   // lane's 4 cj rows / 4
        #pragma unroll
        for (int nt = 0; nt < 4; ++nt) {
            f4v acc = {0.f, 0.f, 0.f, 0.f};
            acc = __builtin_amdgcn_mfma_f32_16x16x32_bf16(afr.v, bfr[nt].v, acc, 0, 0, 0);
            const int b = nt * 16 + (lane & 15);
            const uint2 xq = *(const uint2*)(xT2 + ((size_t)xrow * 64 + b) * 4);
            float p = acc[0] * bflo(xq.x) + acc[1] * bfhi(xq.x)
                    + acc[2] * bflo(xq.y) + acc[3] * bfhi(xq.y);
            p += __shfl_xor(p, 16);             // j 0-3 + 4-7 within each c
            if (!(lane & 16)) {                 // lanes g=0 -> c0, g=2 -> c1
                const int c = (cjb >> 3) + (lane >> 5);
                agr[((size_t)ko * Cn + c) * 64 + b] = p;
            }
        }
    }
}

// ---------------------------------------------------------------------------
// kSmax: in-place softmax over k (axis=1) per (b,c).  cc stays fp32.
// Thread = one (c,b); 32 strided loads are coalesced across the wave.
// ---------------------------------------------------------------------------
__global__ __launch_bounds__(256) void kSmax(float* __restrict__ agr)
{
    const int t = blockIdx.x * 256 + threadIdx.x;   // 0..131071
    float* base = agr + (size_t)(t >> 6) * 64 + (t & 63);
    float a[32];
    float mx = -1e30f;
    #pragma unroll
    for (int k = 0; k < 32; ++k) { a[k] = base[(size_t)k * (Cn * 64)]; mx = fmaxf(mx, a[k]); }
    float sum = 0.f;
    #pragma unroll
    for (int k = 0; k < 32; ++k) { a[k] = __expf(a[k] - mx); sum += a[k]; }
    const float r = 1.0f / sum;
    #pragma unroll
    for (int k = 0; k < 32; ++k) base[(size_t)k * (Cn * 64)] = a[k] * r;
}

// ---------------------------------------------------------------------------
// kGemm2: s[b,k,i] = sum_cj (cc[b,k,c]*x[b,cj]) * W[k,cj,i] via MFMA.
// Same shape as kGemm1 but per-k (N=16) with the A-frag scaled by cc on the
// fly (lane's 8 j's share one c -> one scalar; repack via cvt_pk, RNE).
// Grid 1024 = 32 k x 32 ksplits; 4 waves = 4 m-tiles (all of B).
// ---------------------------------------------------------------------------
__global__ __launch_bounds__(256) void kGemm2(const unsigned short* __restrict__ xb,
                                              const float* __restrict__ W,
                                              const float* __restrict__ cc,
                                              float* __restrict__ part2)
{
    const int ko    = blockIdx.x & 31;
    const int split = blockIdx.x >> 5;        // 0..31
    const int ks0   = split * 16;
    const int lane  = threadIdx.x & 63;
    const int m0    = (threadIdx.x >> 6) * 16;
    const int i     = lane & 15;
    const int cq    = lane >> 4;
    const int bg    = m0 + (lane & 15);

    f4v acc = {0.f, 0.f, 0.f, 0.f};
    const unsigned short* arow = xb + (size_t)bg * KJ + cq * 8;
    const float* ccp = cc + ((size_t)ko * Cn + ks0 * 4 + cq) * 64 + bg;

    for (int s = 0; s < 16; ++s) {
        const int ks = ks0 + s;
        const int c  = ks * 4 + cq;
        const uint4 au = *(const uint4*)(arow + (size_t)ks * 32);
        const float cv = ccp[s * 256];
        U16B af;
        af.u.x = cvtpk(bflo(au.x) * cv, bfhi(au.x) * cv);
        af.u.y = cvtpk(bflo(au.y) * cv, bfhi(au.y) * cv);
        af.u.z = cvtpk(bflo(au.z) * cv, bfhi(au.z) * cv);
        af.u.w = cvtpk(bflo(au.w) * cv, bfhi(au.w) * cv);
        const float* wp = W + (((size_t)ko * Cn + c) * 16 + i) * 8;
        const float4 w0 = *(const float4*)wp;
        const float4 w1 = *(const float4*)(wp + 4);
        U16B bf;
        bf.u.x = cvtpk(w0.x, w0.y); bf.u.y = cvtpk(w0.z, w0.w);
        bf.u.z = cvtpk(w1.x, w1.y); bf.u.w = cvtpk(w1.z, w1.w);
        acc = __builtin_amdgcn_mfma_f32_16x16x32_bf16(af.v, bf.v, acc, 0, 0, 0);
    }

    float* pb = part2 + (size_t)split * NOUT;
    const int col = lane & 15, rbase = (lane >> 4) * 4;
    #pragma unroll
    for (int r = 0; r < 4; ++r)
        pb[(size_t)(m0 + rbase + r) * 512 + ko * 16 + col] = acc[r];
}

// ---------------------------------------------------------------------------
// kSq2: out = squash(sum_splits part2).  No 1/32 here (cc already normalized).
// ---------------------------------------------------------------------------
__global__ __launch_bounds__(256) void kSq2(const float* __restrict__ part2,
                                            float* __restrict__ out)
{
    const int t = blockIdx.x * 256 + threadIdx.x;   // 0..8191
    const size_t o = (size_t)t * 4;
    float4 s = make_float4(0.f, 0.f, 0.f, 0.f);
    #pragma unroll 8
    for (int g = 0; g < KS2; ++g) {
        const float4 p = *(const float4*)(part2 + (size_t)g * NOUT + o);
        s.x += p.x; s.y += p.y; s.z += p.z; s.w += p.w;
    }
    float sq = (s.x * s.x + s.y * s.y) + (s.z * s.z + s.w * s.w);
    sq += __shfl_xor(sq, 1);
    sq += __shfl_xor(sq, 2);
    const float f = (sq / (1.0f + sq)) * rsqrtf(sq + EPSf);
    *(float4*)(out + o) = make_float4(s.x * f, s.y * f, s.z * f, s.w * f);
}

extern "C" void kernel_launch(void* const* d_in, const int* in_sizes, int n_in,
                              void* d_out, int out_size, void* d_ws, size_t ws_size,
                              hipStream_t stream)
{
    const float* x = (const float*)d_in[0];   // [64,2048,8]
    const float* W = (const float*)d_in[1];   // [32,2048,16,8]
    float* out = (float*)d_out;               // [64,32,16]

    // ws layout (float offsets), total 23.13 MB (<= 23.2 MB proven available):
    //   [0 .. 4194304)            agr/cc [k][c][b] fp32 (16 MiB)
    //                             part1 (KS1*NOUT = 2M floats) ALIASES agr[0:2M]
    //                             (part1 dead before kAgr writes agr)
    //   [4194304 .. +524288)      xb bf16 [b][cj]           (2 MiB)
    //   [4718592 .. +524288)      xT2 bf16 [cj/4][b][4]     (2 MiB)
    //   [4718592 .. +1048576)     part2 (KS2*NOUT) ALIASES xT2+next 2 MiB
    //                             (xT2 dead after kAgr; kGemm2 runs later)
    //   [5767168 .. +16384)       v1f bf16 B-frags          (64 KiB)
    float* wsf = (float*)d_ws;
    float*          agr   = wsf;
    float*          part1 = wsf;
    unsigned short* xb    = (unsigned short*)(wsf + 4194304);
    unsigned short* xT2   = (unsigned short*)(wsf + 4194304 + 524288);
    float*          part2 = wsf + 4194304 + 524288;
    unsigned short* v1f   = (unsigned short*)(wsf + 4194304 + 524288 + 1048576);

    kPrepX<<<512,  256, 0, stream>>>(x, xb, xT2);
    kGemm1<<<512,  256, 0, stream>>>(xb, W, part1);
    kSq1  <<<128,  256, 0, stream>>>(part1, v1f);
    kAgr  <<<1024, 256, 0, stream>>>(W, v1f, xT2, agr);
    kSmax <<<512,  256, 0, stream>>>(agr);
    kGemm2<<<1024, 256, 0, stream>>>(xb, W, agr, part2);
    kSq2  <<<32,   256, 0, stream>>>(part2, out);
}